// Round 4
// baseline (578.315 us; speedup 1.0000x reference)
//
#include <hip/hip_runtime.h>
#include <hip/hip_bf16.h>

typedef __bf16 bf16x8 __attribute__((ext_vector_type(8)));
typedef float floatx4 __attribute__((ext_vector_type(4)));
typedef unsigned short ushortx8 __attribute__((ext_vector_type(8)));

#define FP8_MAX 448.0f
#define QEPS 1e-8f

// async 16B global -> LDS (dest must be wave-uniform base + lane*16)
#define GLLDS16(gptr, lptr)                                                          \
  __builtin_amdgcn_global_load_lds((const __attribute__((address_space(1))) void*)(gptr), \
                                   (__attribute__((address_space(3))) void*)(lptr), 16, 0, 0)

// ---------------------------------------------------------------------------
// fp8-e4m3 groupwise pseudo-quantize (group=32 along last dim) -> bf16 dequant
// ---------------------------------------------------------------------------
__global__ __launch_bounds__(256) void quant_dq_kernel(
    const float* __restrict__ src, __hip_bfloat16* __restrict__ dst, long long n)
{
    long long t = (long long)blockIdx.x * blockDim.x + threadIdx.x;
    long long base = t * 8;
    if (base >= n) return;

    const float4 v0 = *(const float4*)(src + base);
    const float4 v1 = *(const float4*)(src + base + 4);

    float am = fmaxf(
        fmaxf(fmaxf(fabsf(v0.x), fabsf(v0.y)), fmaxf(fabsf(v0.z), fabsf(v0.w))),
        fmaxf(fmaxf(fabsf(v1.x), fabsf(v1.y)), fmaxf(fabsf(v1.z), fabsf(v1.w))));
    am = fmaxf(am, __shfl_xor(am, 1));
    am = fmaxf(am, __shfl_xor(am, 2));
    const float scale = fmaxf(am, QEPS) / FP8_MAX;

    int p0 = __builtin_amdgcn_cvt_pk_fp8_f32(v0.x / scale, v0.y / scale, 0, false);
    int p1 = __builtin_amdgcn_cvt_pk_fp8_f32(v0.z / scale, v0.w / scale, 0, false);
    int p2 = __builtin_amdgcn_cvt_pk_fp8_f32(v1.x / scale, v1.y / scale, 0, false);
    int p3 = __builtin_amdgcn_cvt_pk_fp8_f32(v1.z / scale, v1.w / scale, 0, false);

    float r0 = __builtin_amdgcn_cvt_f32_fp8(p0, 0) * scale;
    float r1 = __builtin_amdgcn_cvt_f32_fp8(p0, 1) * scale;
    float r2 = __builtin_amdgcn_cvt_f32_fp8(p1, 0) * scale;
    float r3 = __builtin_amdgcn_cvt_f32_fp8(p1, 1) * scale;
    float r4 = __builtin_amdgcn_cvt_f32_fp8(p2, 0) * scale;
    float r5 = __builtin_amdgcn_cvt_f32_fp8(p2, 1) * scale;
    float r6 = __builtin_amdgcn_cvt_f32_fp8(p3, 0) * scale;
    float r7 = __builtin_amdgcn_cvt_f32_fp8(p3, 1) * scale;

    alignas(16) __hip_bfloat16 hb[8] = {
        __float2bfloat16(r0), __float2bfloat16(r1),
        __float2bfloat16(r2), __float2bfloat16(r3),
        __float2bfloat16(r4), __float2bfloat16(r5),
        __float2bfloat16(r6), __float2bfloat16(r7)};
    *(ushortx8*)(dst + base) = *(const ushortx8*)hb;
}

// ---------------------------------------------------------------------------
// bf16 NT GEMM + bias: 256(M)x128(N) block, BK=32, 256 thr (4 waves 2Mx2N),
// per-wave 128x64 output (8x4 16x16 frags, 0.375 LDS-reads/MFMA), simple
// double-buffered schedule, 48 KiB LDS -> 2 BLOCKS/CU co-resident.
//
// Round-3 post-mortem: 256^2/512-thr was pinned at 1 block/CU (LDS 128K +
// 128-reg acc); all three schedules measured identically (287-297 us) since
// every vmcnt(0)+barrier idled the whole CU. This config keeps the fat
// 128x64 per-wave tile (same read ratio, LDS floor ~184 us/CU) but restores
// cross-block overlap: when block0 drains at its barrier, block1's waves
// keep the LDS port + MFMA pipes busy (m114).
//
// LDS rows are 32 bf16 = 64B = 4 chunks of 16B. Swizzle: LDS chunk c of row
// r holds global chunk c ^ ((r>>1)&3) (applied on the GLOBAL source address;
// LDS dest stays linear as global_load_lds requires). Frag read at chunk
// fq ^ ((fr>>1)&3): consecutive 8 lanes hit bank-groups {0,4,1,5,2,6,3,7}
// (all distinct) -> conflict-free, same property as the round-0 kernel's
// measured-zero-conflict pattern.
//
// WAR safety: staging targets the buffer whose reads retired before the
// previous barrier; RAW by vmcnt(0) before the barrier that publishes.
// Assumes M%256==0, N%128==0, K%64==0 (holds: 8192/4096/4096).
// ---------------------------------------------------------------------------

#define BAR() __builtin_amdgcn_s_barrier()
#define VMCNT(n) asm volatile("s_waitcnt vmcnt(" #n ")" ::: "memory")

// stage one K-tile (A: 256x32 = 4 calls, B: 128x32 = 2 calls; 64 rows/call)
#define STAGE_TILE(t_, b_)                                                    \
  do {                                                                        \
    _Pragma("unroll") for (int r_ = 0; r_ < 4; ++r_)                          \
        GLLDS16(gAs + (long)r_ * 64 * K + (long)(t_) * 32,                    \
                &sA[(b_)][r_ * 2048 + tid * 8]);                              \
    _Pragma("unroll") for (int r_ = 0; r_ < 2; ++r_)                          \
        GLLDS16(gBs + (long)r_ * 64 * K + (long)(t_) * 32,                    \
                &sB[(b_)][r_ * 2048 + tid * 8]);                              \
  } while (0)

// one K-tile of compute: 12 ds_read_b128 + 32 MFMA, no internal fences
// (compiler emits fine-grained lgkmcnt interleave, m97 asm evidence)
#define COMPUTE(b_)                                                           \
  do {                                                                        \
    bf16x8 af[8], bfv[4];                                                     \
    _Pragma("unroll") for (int i_ = 0; i_ < 8; ++i_)                          \
        af[i_] = *(const bf16x8*)(&sA[(b_)][aoff0 + i_ * 512]);               \
    _Pragma("unroll") for (int j_ = 0; j_ < 4; ++j_)                          \
        bfv[j_] = *(const bf16x8*)(&sB[(b_)][boff0 + j_ * 512]);              \
    __builtin_amdgcn_s_setprio(1);                                            \
    _Pragma("unroll") for (int i_ = 0; i_ < 8; ++i_)                          \
    _Pragma("unroll") for (int j_ = 0; j_ < 4; ++j_)                          \
        acc[i_][j_] = __builtin_amdgcn_mfma_f32_16x16x32_bf16(                \
            af[i_], bfv[j_], acc[i_][j_], 0, 0, 0);                           \
    __builtin_amdgcn_s_setprio(0);                                            \
  } while (0)

__global__ __launch_bounds__(256, 2) void gemm_bias_kernel(
    const __hip_bfloat16* __restrict__ A,   // [M][K]
    const __hip_bfloat16* __restrict__ B,   // [N][K]
    const float* __restrict__ bias,         // [N]
    float* __restrict__ C,                  // [M][N]
    int M, int N, int K)
{
    __shared__ __attribute__((aligned(16))) __hip_bfloat16 sA[2][256 * 32];
    __shared__ __attribute__((aligned(16))) __hip_bfloat16 sB[2][128 * 32];

    const int tid  = threadIdx.x;
    const int lane = tid & 63;
    const int wave = tid >> 6;    // 0..3
    const int wm   = wave >> 1;   // 0..1 : 128-row half of M-tile
    const int wn   = wave & 1;    // 0..1 : 64-col half of N-tile

    // T1: XCD-aware bijective block swizzle (nwg = 1024, %8 == 0)
    const int nwg = gridDim.x;
    const int wg  = blockIdx.x;
    int swz = wg;
    if ((nwg & 7) == 0) swz = (wg & 7) * (nwg >> 3) + (wg >> 3);
    const int NXB = N >> 7;                    // blocks along N (128-wide)
    const long bm = (long)(swz / NXB) * 256;
    const long bn = (long)(swz % NXB) * 128;

    // staging: 256 thr * 16B = 4 KiB = 64 rows (64B each) per GLLDS16 call
    const int srow   = tid >> 2;                       // 0..63
    const int schunk = (tid & 3) ^ ((srow >> 1) & 3);  // pre-swizzled chunk
    const __hip_bfloat16* gAs = A + (bm + srow) * (long)K + schunk * 8;
    const __hip_bfloat16* gBs = B + (bn + srow) * (long)K + schunk * 8;

    // fragment read offsets (chunk-XOR matches staging swizzle)
    const int fr = lane & 15;
    const int fq = lane >> 4;
    const int ach  = (fq ^ ((fr >> 1) & 3)) * 8;
    const int aoff0 = (wm * 128 + fr) * 32 + ach;
    const int boff0 = (wn * 64 + fr) * 32 + ach;

    floatx4 acc[8][4];
#pragma unroll
    for (int i = 0; i < 8; ++i)
#pragma unroll
        for (int j = 0; j < 4; ++j)
            acc[i][j] = (floatx4){0.f, 0.f, 0.f, 0.f};

    const int NI = K >> 6;           // iterations of 2 K-tiles (BK=32)

    // prologue: tile0 -> buf0
    STAGE_TILE(0, 0);
    VMCNT(0);
    BAR();

#pragma unroll 1
    for (int i = 0; i < NI; ++i) {
        STAGE_TILE(2 * i + 1, 1);    // buf1 reads retired before prev BAR
        COMPUTE(0);                  // tile 2i
        VMCNT(0);                    // tile 2i+1 landed
        BAR();

        if (i + 1 < NI) STAGE_TILE(2 * i + 2, 0);
        COMPUTE(1);                  // tile 2i+1
        VMCNT(0);
        BAR();
    }

    // epilogue: C/D layout col=lane&15, row=(lane>>4)*4+reg  [m89/m91]
    const int rq = (lane >> 4) * 4;
#pragma unroll
    for (int j = 0; j < 4; ++j) {
        const long gc = bn + wn * 64 + j * 16 + fr;
        const float bj = bias[gc];
#pragma unroll
        for (int mf = 0; mf < 8; ++mf) {
            const long gr = bm + wm * 128 + mf * 16 + rq;
            float* cp = C + gr * (long)N + gc;
#pragma unroll
            for (int r = 0; r < 4; ++r)
                cp[(long)r * N] = acc[mf][j][r] + bj;
        }
    }
}

extern "C" void kernel_launch(void* const* d_in, const int* in_sizes, int n_in,
                              void* d_out, int out_size, void* d_ws, size_t ws_size,
                              hipStream_t stream) {
    const float* x    = (const float*)d_in[0];   // [B,S,K] fp32
    const float* W    = (const float*)d_in[1];   // [N,K]   fp32
    const float* bias = (const float*)d_in[2];   // [N]     fp32
    float* out = (float*)d_out;

    const long long nx = in_sizes[0];
    const long long nw = in_sizes[1];
    const int N = in_sizes[2];
    const int K = (int)(nw / N);
    const int M = (int)(nx / K);

    __hip_bfloat16* xq = (__hip_bfloat16*)d_ws;
    __hip_bfloat16* wq = xq + nx;

    {
        long long tx = nx / 8;
        int blocks = (int)((tx + 255) / 256);
        quant_dq_kernel<<<blocks, 256, 0, stream>>>(x, xq, nx);
    }
    {
        long long tw = nw / 8;
        int blocks = (int)((tw + 255) / 256);
        quant_dq_kernel<<<blocks, 256, 0, stream>>>(W, wq, nw);
    }

    dim3 grid((N / 128) * (M / 256));
    gemm_bias_kernel<<<grid, 256, 0, stream>>>(xq, wq, bias, out, M, N, K);
}

// Round 5
// 566.999 us; speedup vs baseline: 1.0200x; 1.0200x over previous
//
#include <hip/hip_runtime.h>
#include <hip/hip_bf16.h>

typedef __bf16 bf16x8 __attribute__((ext_vector_type(8)));
typedef float floatx4 __attribute__((ext_vector_type(4)));
typedef unsigned short ushortx8 __attribute__((ext_vector_type(8)));

#define FP8_MAX 448.0f
#define QEPS 1e-8f

// async 16B global -> LDS (dest must be wave-uniform base + lane*16)
#define GLLDS16(gptr, lptr)                                                          \
  __builtin_amdgcn_global_load_lds((const __attribute__((address_space(1))) void*)(gptr), \
                                   (__attribute__((address_space(3))) void*)(lptr), 16, 0, 0)

// ---------------------------------------------------------------------------
// fp8-e4m3 groupwise pseudo-quantize (group=32 along last dim) -> bf16 dequant
// FUSED: one launch covers x then W (both group-aligned; per-block branch is
// uniform since nx/8 is a multiple of 256). Arithmetic identical to the
// per-tensor version (exact fp32 div, same cvt order) -> bit-identical out.
// ---------------------------------------------------------------------------
__global__ __launch_bounds__(256) void quant_dq_fused_kernel(
    const float* __restrict__ srcX, __hip_bfloat16* __restrict__ dstX, long long nx,
    const float* __restrict__ srcW, __hip_bfloat16* __restrict__ dstW, long long nw)
{
    long long t = (long long)blockIdx.x * blockDim.x + threadIdx.x;
    long long base = t * 8;
    const float* src;
    __hip_bfloat16* dst;
    if (base < nx) {
        src = srcX; dst = dstX;
    } else {
        base -= nx;
        if (base >= nw) return;
        src = srcW; dst = dstW;
    }

    const float4 v0 = *(const float4*)(src + base);
    const float4 v1 = *(const float4*)(src + base + 4);

    float am = fmaxf(
        fmaxf(fmaxf(fabsf(v0.x), fabsf(v0.y)), fmaxf(fabsf(v0.z), fabsf(v0.w))),
        fmaxf(fmaxf(fabsf(v1.x), fabsf(v1.y)), fmaxf(fabsf(v1.z), fabsf(v1.w))));
    am = fmaxf(am, __shfl_xor(am, 1));
    am = fmaxf(am, __shfl_xor(am, 2));
    const float scale = fmaxf(am, QEPS) / FP8_MAX;

    int p0 = __builtin_amdgcn_cvt_pk_fp8_f32(v0.x / scale, v0.y / scale, 0, false);
    int p1 = __builtin_amdgcn_cvt_pk_fp8_f32(v0.z / scale, v0.w / scale, 0, false);
    int p2 = __builtin_amdgcn_cvt_pk_fp8_f32(v1.x / scale, v1.y / scale, 0, false);
    int p3 = __builtin_amdgcn_cvt_pk_fp8_f32(v1.z / scale, v1.w / scale, 0, false);

    float r0 = __builtin_amdgcn_cvt_f32_fp8(p0, 0) * scale;
    float r1 = __builtin_amdgcn_cvt_f32_fp8(p0, 1) * scale;
    float r2 = __builtin_amdgcn_cvt_f32_fp8(p1, 0) * scale;
    float r3 = __builtin_amdgcn_cvt_f32_fp8(p1, 1) * scale;
    float r4 = __builtin_amdgcn_cvt_f32_fp8(p2, 0) * scale;
    float r5 = __builtin_amdgcn_cvt_f32_fp8(p2, 1) * scale;
    float r6 = __builtin_amdgcn_cvt_f32_fp8(p3, 0) * scale;
    float r7 = __builtin_amdgcn_cvt_f32_fp8(p3, 1) * scale;

    alignas(16) __hip_bfloat16 hb[8] = {
        __float2bfloat16(r0), __float2bfloat16(r1),
        __float2bfloat16(r2), __float2bfloat16(r3),
        __float2bfloat16(r4), __float2bfloat16(r5),
        __float2bfloat16(r6), __float2bfloat16(r7)};
    *(ushortx8*)(dst + base) = *(const ushortx8*)hb;
}

// ---------------------------------------------------------------------------
// bf16 NT GEMM + bias:  C[m][n] = sum_k A[m][k]*B[n][k] + bias[n]
// ROUND-0 WINNER restored verbatim (260 us, MfmaUtil 50%, 3 blocks/CU):
// 128x128 block, BK=64 (32 MFMA per barrier pair), 4 waves (2x2), 16x16x32
// MFMA 4x4/wave, global_load_lds width-16 staging, XOR-swizzled LDS chunks.
// ONLY change vs round 0: 1-D grid + T1 XCD-aware bijective block swizzle
// (nwg=2048 %8==0) -- round-0 had none; FETCH was 495 MB vs ~100 ideal, so
// chunking 256 consecutive tiles per XCD gives each XCD an A-panel (1 MB,
// L2-resident) reused across 32 N-tiles.
// ---------------------------------------------------------------------------
__global__ __launch_bounds__(256, 2) void gemm_bias_kernel(
    const __hip_bfloat16* __restrict__ A,   // [M][K]
    const __hip_bfloat16* __restrict__ B,   // [N][K]
    const float* __restrict__ bias,         // [N]
    float* __restrict__ C,                  // [M][N]
    int M, int N, int K)
{
    __shared__ __attribute__((aligned(16))) __hip_bfloat16 As[128 * 64];
    __shared__ __attribute__((aligned(16))) __hip_bfloat16 Bs[128 * 64];

    const int tid  = threadIdx.x;
    const int lane = tid & 63;
    const int wave = tid >> 6;
    const int wr   = (wave >> 1) * 64;   // wave row offset in block tile
    const int wc   = (wave & 1) * 64;    // wave col offset in block tile

    // T1: XCD-aware bijective swizzle of the flat block id
    const int nwg = gridDim.x;
    const int wg  = blockIdx.x;
    int swz = wg;
    if ((nwg & 7) == 0) swz = (wg & 7) * (nwg >> 3) + (wg >> 3);
    const int NXB = N >> 7;                       // tiles along N
    const long bm = (long)(swz / NXB) * 128;
    const long bn = (long)(swz % NXB) * 128;

    // staging: 8 chunks of 8 bf16 per 64-col row; 8 threads/row; 32 rows/call
    const int srow = tid >> 3;                       // 0..31
    const int scg  = (tid & 7) ^ (srow & 7);         // swizzled global chunk

    const __hip_bfloat16* gA = A + (bm + srow) * (long)K + scg * 8;
    const __hip_bfloat16* gB = B + (bn + srow) * (long)K + scg * 8;
    const long rstep = 32 * (long)K;                 // 32 rows per call

    __hip_bfloat16* lA = As + tid * 8;               // call r adds r*32*64 elems
    __hip_bfloat16* lB = Bs + tid * 8;

    floatx4 acc[4][4];
#pragma unroll
    for (int i = 0; i < 4; ++i)
#pragma unroll
        for (int j = 0; j < 4; ++j)
            acc[i][j] = (floatx4){0.f, 0.f, 0.f, 0.f};

    const int fr = lane & 15;            // row/col within 16-tile
    const int fq = lane >> 4;            // k-quad: chunk g = ks*4 + fq

    for (int k0 = 0; k0 < K; k0 += 64) {
#pragma unroll
        for (int r = 0; r < 4; ++r) {
            GLLDS16(gA + k0 + r * rstep, lA + r * 32 * 64);
            GLLDS16(gB + k0 + r * rstep, lB + r * 32 * 64);
        }
        __syncthreads();

#pragma unroll
        for (int ks = 0; ks < 2; ++ks) {
            bf16x8 af[4], bfv[4];
#pragma unroll
            for (int i = 0; i < 4; ++i) {
                const int ra = wr + i * 16 + fr;
                af[i] = *(const bf16x8*)(As + ra * 64 + (((ks * 4 + fq) ^ (ra & 7)) * 8));
            }
#pragma unroll
            for (int j = 0; j < 4; ++j) {
                const int rb = wc + j * 16 + fr;
                bfv[j] = *(const bf16x8*)(Bs + rb * 64 + (((ks * 4 + fq) ^ (rb & 7)) * 8));
            }
#pragma unroll
            for (int i = 0; i < 4; ++i)
#pragma unroll
                for (int j = 0; j < 4; ++j)
                    acc[i][j] = __builtin_amdgcn_mfma_f32_16x16x32_bf16(af[i], bfv[j], acc[i][j], 0, 0, 0);
        }
        __syncthreads();
    }

    // epilogue: C/D layout col=lane&15, row=(lane>>4)*4+reg  [m89/m91]
    const int rq = (lane >> 4) * 4;
#pragma unroll
    for (int j = 0; j < 4; ++j) {
        const long gc = bn + wc + j * 16 + fr;
        const float bj = bias[gc];
#pragma unroll
        for (int i = 0; i < 4; ++i) {
            const long gr = bm + wr + i * 16 + rq;
            float* cp = C + gr * (long)N + gc;
#pragma unroll
            for (int r = 0; r < 4; ++r)
                cp[(long)r * N] = acc[i][j][r] + bj;
        }
    }
}

extern "C" void kernel_launch(void* const* d_in, const int* in_sizes, int n_in,
                              void* d_out, int out_size, void* d_ws, size_t ws_size,
                              hipStream_t stream) {
    const float* x    = (const float*)d_in[0];   // [B,S,K] fp32
    const float* W    = (const float*)d_in[1];   // [N,K]   fp32
    const float* bias = (const float*)d_in[2];   // [N]     fp32
    float* out = (float*)d_out;

    const long long nx = in_sizes[0];
    const long long nw = in_sizes[1];
    const int N = in_sizes[2];
    const int K = (int)(nw / N);
    const int M = (int)(nx / K);

    __hip_bfloat16* xq = (__hip_bfloat16*)d_ws;
    __hip_bfloat16* wq = xq + nx;

    {
        long long tt = (nx + nw) / 8;
        int blocks = (int)((tt + 255) / 256);
        quant_dq_fused_kernel<<<blocks, 256, 0, stream>>>(x, xq, nx, W, wq, nw);
    }

    dim3 grid((N / 128) * (M / 128));
    gemm_bias_kernel<<<grid, 256, 0, stream>>>(xq, wq, bias, out, M, N, K);
}